// Round 1
// baseline (4467.882 us; speedup 1.0000x reference)
//
#include <hip/hip_runtime.h>

#define NB 8
#define NP 4096
#define NS 1024

// ============================ FPS =============================
// One block per cloud. Exact match of the reference scan:
// out[0]=0; for t in 1..S-1: min_d=min(min_d,d2(last)); out[t]=argmax(min_d)
__global__ __launch_bounds__(512) void fps_kernel(
        const float* __restrict__ pos,
        float* __restrict__ centers,
        float* __restrict__ out_pos,
        float* __restrict__ out_batch) {
#pragma clang fp contract(off)
    const int b = blockIdx.x;
    const int tid = threadIdx.x;
    const int lane = tid & 63;
    const int wid = tid >> 6;
    __shared__ float spx[NP], spy[NP], spz[NP];
    __shared__ float wval[8];
    __shared__ int widx[8];

    const float* pb = pos + (size_t)b * NP * 3;
    float px[8], py[8], pz[8], md[8];
#pragma unroll
    for (int j = 0; j < 8; ++j) {
        int p = tid + j * 512;
        float xx = pb[p * 3 + 0];
        float yy = pb[p * 3 + 1];
        float zz = pb[p * 3 + 2];
        px[j] = xx; py[j] = yy; pz[j] = zz;
        md[j] = __builtin_inff();
        spx[p] = xx; spy[p] = yy; spz[p] = zz;
    }
    for (int t = tid; t < NS; t += 512) out_batch[b * NS + t] = (float)b;
    __syncthreads();

    int last = 0;
    if (tid == 0) {
        size_t o = (size_t)(b * NS) * 3;
        centers[o + 0] = spx[0]; centers[o + 1] = spy[0]; centers[o + 2] = spz[0];
        out_pos[o + 0] = spx[0]; out_pos[o + 1] = spy[0]; out_pos[o + 2] = spz[0];
    }

    for (int t = 1; t < NS; ++t) {
        float cx = spx[last], cy = spy[last], cz = spz[last];
        float bv = -1.0f;
        int bi = 0;
#pragma unroll
        for (int j = 0; j < 8; ++j) {
            float dx = px[j] - cx; float sx = dx * dx;
            float dy = py[j] - cy; float sy = dy * dy;
            float dz = pz[j] - cz; float sz = dz * dz;
            float d = sx + sy; d = d + sz;
            float m = fminf(md[j], d);
            md[j] = m;
            int p = tid + j * 512;
            if (m > bv) { bv = m; bi = p; }  // ascending p -> strict > keeps first max
        }
        // wave-level argmax (min index on ties)
#pragma unroll
        for (int off = 1; off < 64; off <<= 1) {
            float ov = __shfl_xor(bv, off);
            int oi = __shfl_xor(bi, off);
            if (ov > bv || (ov == bv && oi < bi)) { bv = ov; bi = oi; }
        }
        if (lane == 0) { wval[wid] = bv; widx[wid] = bi; }
        __syncthreads();
        bv = wval[0]; bi = widx[0];
#pragma unroll
        for (int w = 1; w < 8; ++w) {
            float ov = wval[w]; int oi = widx[w];
            if (ov > bv || (ov == bv && oi < bi)) { bv = ov; bi = oi; }
        }
        last = bi;
        if (tid == 0) {
            size_t o = (size_t)(b * NS + t) * 3;
            centers[o + 0] = spx[bi]; centers[o + 1] = spy[bi]; centers[o + 2] = spz[bi];
            out_pos[o + 0] = spx[bi]; out_pos[o + 1] = spy[bi]; out_pos[o + 2] = spz[bi];
        }
        __syncthreads();
    }
}

// ========================= Selection ==========================
// Exact K-nearest within radius r via binary search on uint(d2) bits.
// One wave per center, 32 centers per block (shared LDS copy of the cloud).
template <int K>
__global__ __launch_bounds__(256) void select_kernel(
        const float* __restrict__ pos,
        const float* __restrict__ centers,
        int* __restrict__ nbr,
        int* __restrict__ nvalid,
        float r2) {
#pragma clang fp contract(off)
    __shared__ float spx[NP], spy[NP], spz[NP];
    const int G = 32;
    const int cbase = blockIdx.x * G;
    const int b = cbase / NS;
    const float* pb = pos + (size_t)b * NP * 3;
    for (int p = threadIdx.x; p < NP; p += 256) {
        spx[p] = pb[p * 3 + 0];
        spy[p] = pb[p * 3 + 1];
        spz[p] = pb[p * 3 + 2];
    }
    __syncthreads();

    const int lane = threadIdx.x & 63;
    const int wid = threadIdx.x >> 6;
    const unsigned kr2 = __float_as_uint(r2);

    for (int c = wid; c < G; c += 4) {
        const int cid = cbase + c;
        const float cx = centers[cid * 3 + 0];
        const float cy = centers[cid * 3 + 1];
        const float cz = centers[cid * 3 + 2];
        unsigned key[64];
#pragma unroll
        for (int i = 0; i < 64; ++i) {
            int p = lane + i * 64;
            float dx = spx[p] - cx; float sx = dx * dx;
            float dy = spy[p] - cy; float sy = dy * dy;
            float dz = spz[p] - cz; float sz = dz * dz;
            float d2 = sx + sy; d2 = d2 + sz;
            key[i] = __float_as_uint(d2);
        }
        int c_cnt = 0;
#pragma unroll
        for (int i = 0; i < 64; ++i)
            c_cnt += __popcll(__ballot(key[i] <= kr2));

        const unsigned long long below = (1ull << lane) - 1ull;
        int nv;
        if (c_cnt <= K) {
            nv = c_cnt;
            int base = 0;
#pragma unroll
            for (int i = 0; i < 64; ++i) {
                unsigned long long m = __ballot(key[i] <= kr2);
                if (key[i] <= kr2) {
                    int slot = base + __popcll(m & below);
                    nbr[(size_t)cid * K + slot] = lane + i * 64;
                }
                base += __popcll(m);
            }
        } else {
            nv = K;
            unsigned lo = 0, hi = kr2;
            while (lo < hi) {
                unsigned mid = lo + ((hi - lo) >> 1);
                int cnt = 0;
#pragma unroll
                for (int i = 0; i < 64; ++i)
                    cnt += __popcll(__ballot(key[i] <= mid));
                if (cnt >= K) hi = mid; else lo = mid + 1;
            }
            const unsigned t = lo;  // K-th smallest key
            int m_cnt = 0;
#pragma unroll
            for (int i = 0; i < 64; ++i)
                m_cnt += __popcll(__ballot(key[i] < t));
            const int rem = K - m_cnt;
            int base = 0, ties = 0;
#pragma unroll
            for (int i = 0; i < 64; ++i) {
                unsigned long long lt = __ballot(key[i] < t);
                unsigned long long eq = __ballot(key[i] == t);
                if (key[i] < t) {
                    int slot = base + __popcll(lt & below);
                    nbr[(size_t)cid * K + slot] = lane + i * 64;
                } else if (key[i] == t) {
                    int tr = ties + __popcll(eq & below);
                    if (tr < rem) nbr[(size_t)cid * K + (m_cnt + tr)] = lane + i * 64;
                }
                base += __popcll(lt);
                ties += __popcll(eq);
            }
        }
        if (lane == 0) nvalid[cid] = nv;
    }
}

// =========================== MLP ==============================
template <int CK, int CIN_, int COUT, int KT>
__device__ __forceinline__ void layer_fwd(const float* __restrict__ in,
                                          const float* __restrict__ W,
                                          const float* __restrict__ bias,
                                          float* __restrict__ out, int tid) {
    constexpr int CG = COUT / 4;
    constexpr int ITEMS = CG * (CK / KT);
    for (int item = tid; item < ITEMS; item += 256) {
        const int c4 = (item % CG) * 4;
        const int kb = (item / CG) * KT;
        const float4 bb = *(const float4*)&bias[c4];
        float acc[KT][4];
#pragma unroll
        for (int kk = 0; kk < KT; ++kk) {
            acc[kk][0] = bb.x; acc[kk][1] = bb.y; acc[kk][2] = bb.z; acc[kk][3] = bb.w;
        }
#pragma unroll 2
        for (int cin = 0; cin < CIN_; ++cin) {
            const float4 w = *(const float4*)&W[(size_t)cin * COUT + c4];
#pragma unroll
            for (int kk = 0; kk < KT; ++kk) {
                float f = in[(kb + kk) * CIN_ + cin];
                acc[kk][0] = fmaf(f, w.x, acc[kk][0]);
                acc[kk][1] = fmaf(f, w.y, acc[kk][1]);
                acc[kk][2] = fmaf(f, w.z, acc[kk][2]);
                acc[kk][3] = fmaf(f, w.w, acc[kk][3]);
            }
        }
#pragma unroll
        for (int kk = 0; kk < KT; ++kk) {
            float4 o;
            o.x = fmaxf(acc[kk][0], 0.f);
            o.y = fmaxf(acc[kk][1], 0.f);
            o.z = fmaxf(acc[kk][2], 0.f);
            o.w = fmaxf(acc[kk][3], 0.f);
            *(float4*)&out[(kb + kk) * COUT + c4] = o;
        }
    }
}

template <int CK, int CIN_, int COUT, int KT>
__device__ __forceinline__ void layer_last(const float* __restrict__ in,
                                           const float* __restrict__ W,
                                           const float* __restrict__ bias,
                                           int* __restrict__ outmax, int tid,
                                           int kvalid) {
    constexpr int CG = COUT / 4;
    constexpr int ITEMS = CG * (CK / KT);
    for (int item = tid; item < ITEMS; item += 256) {
        const int c4 = (item % CG) * 4;
        const int kb = (item / CG) * KT;
        const float4 bb = *(const float4*)&bias[c4];
        float acc[KT][4];
#pragma unroll
        for (int kk = 0; kk < KT; ++kk) {
            acc[kk][0] = bb.x; acc[kk][1] = bb.y; acc[kk][2] = bb.z; acc[kk][3] = bb.w;
        }
#pragma unroll 2
        for (int cin = 0; cin < CIN_; ++cin) {
            const float4 w = *(const float4*)&W[(size_t)cin * COUT + c4];
#pragma unroll
            for (int kk = 0; kk < KT; ++kk) {
                float f = in[(kb + kk) * CIN_ + cin];
                acc[kk][0] = fmaf(f, w.x, acc[kk][0]);
                acc[kk][1] = fmaf(f, w.y, acc[kk][1]);
                acc[kk][2] = fmaf(f, w.z, acc[kk][2]);
                acc[kk][3] = fmaf(f, w.w, acc[kk][3]);
            }
        }
#pragma unroll
        for (int kk = 0; kk < KT; ++kk) {
            if (kb + kk < kvalid) {
                // relu outputs >= 0 -> IEEE bits are int-monotone, init 0 is exact
                atomicMax(&outmax[c4 + 0], __float_as_int(fmaxf(acc[kk][0], 0.f)));
                atomicMax(&outmax[c4 + 1], __float_as_int(fmaxf(acc[kk][1], 0.f)));
                atomicMax(&outmax[c4 + 2], __float_as_int(fmaxf(acc[kk][2], 0.f)));
                atomicMax(&outmax[c4 + 3], __float_as_int(fmaxf(acc[kk][3], 0.f)));
            }
        }
    }
}

template <int K, int CK, int C1, int C2, int C3, int OFF>
__global__ __launch_bounds__(256) void mlp_kernel(
        const float* __restrict__ x, const float* __restrict__ pos,
        const float* __restrict__ centers,
        const int* __restrict__ nbr, const int* __restrict__ nvalid,
        const float* __restrict__ W1, const float* __restrict__ b1,
        const float* __restrict__ W2, const float* __restrict__ b2,
        const float* __restrict__ W3, const float* __restrict__ b3,
        float* __restrict__ out) {
    constexpr int CINF = 67;
    __shared__ __align__(16) float feat[CK * CINF];
    __shared__ __align__(16) float h1[CK * C1];
    __shared__ __align__(16) float h2[CK * C2];
    __shared__ int outmax[C3];
    const int cid = blockIdx.x;
    const int b = cid >> 10;
    const int tid = threadIdx.x;
    const int lane = tid & 63;
    const int wid = tid >> 6;
    const int nv = nvalid[cid];
    const float cx = centers[cid * 3 + 0];
    const float cy = centers[cid * 3 + 1];
    const float cz = centers[cid * 3 + 2];
    for (int i = tid; i < C3; i += 256) outmax[i] = 0;

    for (int k0 = 0; k0 < nv; k0 += CK) {
        __syncthreads();  // protect feat/h reuse and outmax init
        for (int kk = wid; kk < CK; kk += 4) {
            int k = k0 + kk;
            if (k < nv) {
                int pt = nbr[(size_t)cid * K + k];
                const float* xr = x + ((size_t)(b * NP) + pt) * 64;
                feat[kk * CINF + lane] = xr[lane];
                if (lane < 3) {
                    const float* pr = pos + ((size_t)(b * NP) + pt) * 3;
                    float cc = (lane == 0) ? cx : ((lane == 1) ? cy : cz);
                    feat[kk * CINF + 64 + lane] = pr[lane] - cc;
                }
            } else {
                feat[kk * CINF + lane] = 0.f;
                if (lane < 3) feat[kk * CINF + 64 + lane] = 0.f;
            }
        }
        __syncthreads();
        layer_fwd<CK, CINF, C1, 4>(feat, W1, b1, h1, tid);
        __syncthreads();
        layer_fwd<CK, C1, C2, 4>(h1, W2, b2, h2, tid);
        __syncthreads();
        layer_last<CK, C2, C3, 4>(h2, W3, b3, outmax, tid, nv - k0);
    }
    __syncthreads();
    for (int i = tid; i < C3; i += 256)
        out[(size_t)cid * 640 + OFF + i] = __int_as_float(outmax[i]);
}

// ========================= launcher ===========================
extern "C" void kernel_launch(void* const* d_in, const int* in_sizes, int n_in,
                              void* d_out, int out_size, void* d_ws, size_t ws_size,
                              hipStream_t stream) {
    const float* x = (const float*)d_in[0];
    const float* pos = (const float*)d_in[1];
    const float* W0_0 = (const float*)d_in[3];
    const float* b0_0 = (const float*)d_in[4];
    const float* W0_1 = (const float*)d_in[5];
    const float* b0_1 = (const float*)d_in[6];
    const float* W0_2 = (const float*)d_in[7];
    const float* b0_2 = (const float*)d_in[8];
    const float* W1_0 = (const float*)d_in[9];
    const float* b1_0 = (const float*)d_in[10];
    const float* W1_1 = (const float*)d_in[11];
    const float* b1_1 = (const float*)d_in[12];
    const float* W1_2 = (const float*)d_in[13];
    const float* b1_2 = (const float*)d_in[14];
    const float* W2_0 = (const float*)d_in[15];
    const float* b2_0 = (const float*)d_in[16];
    const float* W2_1 = (const float*)d_in[17];
    const float* b2_1 = (const float*)d_in[18];
    const float* W2_2 = (const float*)d_in[19];
    const float* b2_2 = (const float*)d_in[20];

    float* out = (float*)d_out;
    char* ws = (char*)d_ws;
    float* centers = (float*)(ws + 0);                 //  8192*3 f32   = 98304 B
    int* nbr0 = (int*)(ws + 98304);                    //  8192*16 i32  = 524288 B
    int* nbr1 = (int*)(ws + 622592);                   //  8192*32 i32  = 1048576 B
    int* nbr2 = (int*)(ws + 1671168);                  //  8192*64 i32  = 2097152 B
    int* nval = (int*)(ws + 3768320);                  //  3*8192 i32   = 98304 B

    float* out_pos = out + (size_t)8192 * 640;
    float* out_batch = out_pos + (size_t)8192 * 3;

    fps_kernel<<<dim3(NB), dim3(512), 0, stream>>>(pos, centers, out_pos, out_batch);

    select_kernel<16><<<dim3(256), dim3(256), 0, stream>>>(pos, centers, nbr0, nval, (float)(0.1 * 0.1));
    select_kernel<32><<<dim3(256), dim3(256), 0, stream>>>(pos, centers, nbr1, nval + 8192, (float)(0.2 * 0.2));
    select_kernel<64><<<dim3(256), dim3(256), 0, stream>>>(pos, centers, nbr2, nval + 16384, (float)(0.4 * 0.4));

    mlp_kernel<16, 16, 64, 64, 128, 0><<<dim3(8192), dim3(256), 0, stream>>>(
        x, pos, centers, nbr0, nval, W0_0, b0_0, W0_1, b0_1, W0_2, b0_2, out);
    mlp_kernel<32, 32, 128, 128, 256, 128><<<dim3(8192), dim3(256), 0, stream>>>(
        x, pos, centers, nbr1, nval + 8192, W1_0, b1_0, W1_1, b1_1, W1_2, b1_2, out);
    mlp_kernel<64, 32, 128, 128, 256, 384><<<dim3(8192), dim3(256), 0, stream>>>(
        x, pos, centers, nbr2, nval + 16384, W2_0, b2_0, W2_1, b2_1, W2_2, b2_2, out);
}

// Round 2
// 3696.229 us; speedup vs baseline: 1.2088x; 1.2088x over previous
//
#include <hip/hip_runtime.h>

#define NB 8
#define NP 4096
#define NS 1024

// ============================ FPS =============================
// One block per cloud, 256 threads (4 waves), 16 points/thread in registers.
// Exact match of the reference scan: out[0]=0; for t: min_d=min(min_d,d2(last));
// out[t]=argmax(min_d) (first index on ties).
// Argmax carried as u64 key = (f32bits(min_d) << 32) | (NP-1-p): u64-max ==
// (max value, then min index). One barrier/iter via parity double-buffer.
__global__ __launch_bounds__(256) void fps_kernel(
        const float* __restrict__ pos,
        float* __restrict__ centers,
        float* __restrict__ out_pos,
        float* __restrict__ out_batch) {
#pragma clang fp contract(off)
    const int b = blockIdx.x;
    const int tid = threadIdx.x;
    const int lane = tid & 63;
    const int wid = tid >> 6;
    __shared__ float spx[NP], spy[NP], spz[NP];
    __shared__ unsigned long long wred[8];   // 2 parities x 4 waves

    const float* pb = pos + (size_t)b * NP * 3;
    float px[16], py[16], pz[16], md[16];
#pragma unroll
    for (int j = 0; j < 16; ++j) {
        int p = tid + j * 256;
        float xx = pb[p * 3 + 0];
        float yy = pb[p * 3 + 1];
        float zz = pb[p * 3 + 2];
        px[j] = xx; py[j] = yy; pz[j] = zz;
        md[j] = __builtin_inff();
        spx[p] = xx; spy[p] = yy; spz[p] = zz;
    }
    for (int t = tid; t < NS; t += 256) out_batch[b * NS + t] = (float)b;
    __syncthreads();

    float cx = spx[0], cy = spy[0], cz = spz[0];   // broadcast read
    if (tid == 0) {
        size_t o = (size_t)(b * NS) * 3;
        centers[o + 0] = cx; centers[o + 1] = cy; centers[o + 2] = cz;
        out_pos[o + 0] = cx; out_pos[o + 1] = cy; out_pos[o + 2] = cz;
    }

    int par = 0;
    for (int t = 1; t < NS; ++t) {
        // per-thread distance update + argmax (first index on ties: strict >)
        float bv = -1.0f;
        int bj = 0;
#pragma unroll
        for (int j = 0; j < 16; ++j) {
            float dx = px[j] - cx; float sx = dx * dx;
            float dy = py[j] - cy; float sy = dy * dy;
            float dz = pz[j] - cz; float sz = dz * dz;
            float d = sx + sy; d = d + sz;
            float m = fminf(md[j], d);
            md[j] = m;
            if (m > bv) { bv = m; bj = j; }   // ascending j -> ascending p
        }
        const int bp = tid + bj * 256;
        unsigned long long best =
            ((unsigned long long)__float_as_uint(bv) << 32) |
            (unsigned)(NP - 1 - bp);
        // wave u64-max reduction
#pragma unroll
        for (int off = 1; off < 64; off <<= 1) {
            unsigned lo = __shfl_xor((unsigned)best, off);
            unsigned hi = __shfl_xor((unsigned)(best >> 32), off);
            unsigned long long o = ((unsigned long long)hi << 32) | lo;
            best = (o > best) ? o : best;
        }
        if (lane == 0) wred[par * 4 + wid] = best;
        __syncthreads();
        {
            unsigned long long b0 = wred[par * 4 + 0];
            unsigned long long b1 = wred[par * 4 + 1];
            unsigned long long b2 = wred[par * 4 + 2];
            unsigned long long b3 = wred[par * 4 + 3];
            unsigned long long m01 = b0 > b1 ? b0 : b1;
            unsigned long long m23 = b2 > b3 ? b2 : b3;
            best = m01 > m23 ? m01 : m23;
        }
        const int bi = NP - 1 - (int)(best & 0xffffffffu);
        cx = spx[bi]; cy = spy[bi]; cz = spz[bi];   // broadcast reads
        if (tid == 0) {
            size_t o = (size_t)(b * NS + t) * 3;
            centers[o + 0] = cx; centers[o + 1] = cy; centers[o + 2] = cz;
            out_pos[o + 0] = cx; out_pos[o + 1] = cy; out_pos[o + 2] = cz;
        }
        par ^= 1;
    }
}

// ========================= Selection ==========================
// Exact K-nearest within radius r via binary search on uint(d2) bits.
// One wave per center, 32 centers per block (shared LDS copy of the cloud).
template <int K>
__global__ __launch_bounds__(256) void select_kernel(
        const float* __restrict__ pos,
        const float* __restrict__ centers,
        int* __restrict__ nbr,
        int* __restrict__ nvalid,
        float r2) {
#pragma clang fp contract(off)
    __shared__ float spx[NP], spy[NP], spz[NP];
    const int G = 32;
    const int cbase = blockIdx.x * G;
    const int b = cbase / NS;
    const float* pb = pos + (size_t)b * NP * 3;
    for (int p = threadIdx.x; p < NP; p += 256) {
        spx[p] = pb[p * 3 + 0];
        spy[p] = pb[p * 3 + 1];
        spz[p] = pb[p * 3 + 2];
    }
    __syncthreads();

    const int lane = threadIdx.x & 63;
    const int wid = threadIdx.x >> 6;
    const unsigned kr2 = __float_as_uint(r2);

    for (int c = wid; c < G; c += 4) {
        const int cid = cbase + c;
        const float cx = centers[cid * 3 + 0];
        const float cy = centers[cid * 3 + 1];
        const float cz = centers[cid * 3 + 2];
        unsigned key[64];
#pragma unroll
        for (int i = 0; i < 64; ++i) {
            int p = lane + i * 64;
            float dx = spx[p] - cx; float sx = dx * dx;
            float dy = spy[p] - cy; float sy = dy * dy;
            float dz = spz[p] - cz; float sz = dz * dz;
            float d2 = sx + sy; d2 = d2 + sz;
            key[i] = __float_as_uint(d2);
        }
        int c_cnt = 0;
#pragma unroll
        for (int i = 0; i < 64; ++i)
            c_cnt += __popcll(__ballot(key[i] <= kr2));

        const unsigned long long below = (1ull << lane) - 1ull;
        int nv;
        if (c_cnt <= K) {
            nv = c_cnt;
            int base = 0;
#pragma unroll
            for (int i = 0; i < 64; ++i) {
                unsigned long long m = __ballot(key[i] <= kr2);
                if (key[i] <= kr2) {
                    int slot = base + __popcll(m & below);
                    nbr[(size_t)cid * K + slot] = lane + i * 64;
                }
                base += __popcll(m);
            }
        } else {
            nv = K;
            unsigned lo = 0, hi = kr2;
            while (lo < hi) {
                unsigned mid = lo + ((hi - lo) >> 1);
                int cnt = 0;
#pragma unroll
                for (int i = 0; i < 64; ++i)
                    cnt += __popcll(__ballot(key[i] <= mid));
                if (cnt >= K) hi = mid; else lo = mid + 1;
            }
            const unsigned t = lo;  // K-th smallest key
            int m_cnt = 0;
#pragma unroll
            for (int i = 0; i < 64; ++i)
                m_cnt += __popcll(__ballot(key[i] < t));
            const int rem = K - m_cnt;
            int base = 0, ties = 0;
#pragma unroll
            for (int i = 0; i < 64; ++i) {
                unsigned long long lt = __ballot(key[i] < t);
                unsigned long long eq = __ballot(key[i] == t);
                if (key[i] < t) {
                    int slot = base + __popcll(lt & below);
                    nbr[(size_t)cid * K + slot] = lane + i * 64;
                } else if (key[i] == t) {
                    int tr = ties + __popcll(eq & below);
                    if (tr < rem) nbr[(size_t)cid * K + (m_cnt + tr)] = lane + i * 64;
                }
                base += __popcll(lt);
                ties += __popcll(eq);
            }
        }
        if (lane == 0) nvalid[cid] = nv;
    }
}

// =========================== MLP ==============================
template <int CK, int CIN_, int COUT, int KT>
__device__ __forceinline__ void layer_fwd(const float* __restrict__ in,
                                          const float* __restrict__ W,
                                          const float* __restrict__ bias,
                                          float* __restrict__ out, int tid) {
    constexpr int CG = COUT / 4;
    constexpr int ITEMS = CG * (CK / KT);
    for (int item = tid; item < ITEMS; item += 256) {
        const int c4 = (item % CG) * 4;
        const int kb = (item / CG) * KT;
        const float4 bb = *(const float4*)&bias[c4];
        float acc[KT][4];
#pragma unroll
        for (int kk = 0; kk < KT; ++kk) {
            acc[kk][0] = bb.x; acc[kk][1] = bb.y; acc[kk][2] = bb.z; acc[kk][3] = bb.w;
        }
#pragma unroll 2
        for (int cin = 0; cin < CIN_; ++cin) {
            const float4 w = *(const float4*)&W[(size_t)cin * COUT + c4];
#pragma unroll
            for (int kk = 0; kk < KT; ++kk) {
                float f = in[(kb + kk) * CIN_ + cin];
                acc[kk][0] = fmaf(f, w.x, acc[kk][0]);
                acc[kk][1] = fmaf(f, w.y, acc[kk][1]);
                acc[kk][2] = fmaf(f, w.z, acc[kk][2]);
                acc[kk][3] = fmaf(f, w.w, acc[kk][3]);
            }
        }
#pragma unroll
        for (int kk = 0; kk < KT; ++kk) {
            float4 o;
            o.x = fmaxf(acc[kk][0], 0.f);
            o.y = fmaxf(acc[kk][1], 0.f);
            o.z = fmaxf(acc[kk][2], 0.f);
            o.w = fmaxf(acc[kk][3], 0.f);
            *(float4*)&out[(kb + kk) * COUT + c4] = o;
        }
    }
}

template <int CK, int CIN_, int COUT, int KT>
__device__ __forceinline__ void layer_last(const float* __restrict__ in,
                                           const float* __restrict__ W,
                                           const float* __restrict__ bias,
                                           int* __restrict__ outmax, int tid,
                                           int kvalid) {
    constexpr int CG = COUT / 4;
    constexpr int ITEMS = CG * (CK / KT);
    for (int item = tid; item < ITEMS; item += 256) {
        const int c4 = (item % CG) * 4;
        const int kb = (item / CG) * KT;
        const float4 bb = *(const float4*)&bias[c4];
        float acc[KT][4];
#pragma unroll
        for (int kk = 0; kk < KT; ++kk) {
            acc[kk][0] = bb.x; acc[kk][1] = bb.y; acc[kk][2] = bb.z; acc[kk][3] = bb.w;
        }
#pragma unroll 2
        for (int cin = 0; cin < CIN_; ++cin) {
            const float4 w = *(const float4*)&W[(size_t)cin * COUT + c4];
#pragma unroll
            for (int kk = 0; kk < KT; ++kk) {
                float f = in[(kb + kk) * CIN_ + cin];
                acc[kk][0] = fmaf(f, w.x, acc[kk][0]);
                acc[kk][1] = fmaf(f, w.y, acc[kk][1]);
                acc[kk][2] = fmaf(f, w.z, acc[kk][2]);
                acc[kk][3] = fmaf(f, w.w, acc[kk][3]);
            }
        }
#pragma unroll
        for (int kk = 0; kk < KT; ++kk) {
            if (kb + kk < kvalid) {
                // relu outputs >= 0 -> IEEE bits are int-monotone, init 0 is exact
                atomicMax(&outmax[c4 + 0], __float_as_int(fmaxf(acc[kk][0], 0.f)));
                atomicMax(&outmax[c4 + 1], __float_as_int(fmaxf(acc[kk][1], 0.f)));
                atomicMax(&outmax[c4 + 2], __float_as_int(fmaxf(acc[kk][2], 0.f)));
                atomicMax(&outmax[c4 + 3], __float_as_int(fmaxf(acc[kk][3], 0.f)));
            }
        }
    }
}

template <int K, int CK, int C1, int C2, int C3, int OFF>
__global__ __launch_bounds__(256) void mlp_kernel(
        const float* __restrict__ x, const float* __restrict__ pos,
        const float* __restrict__ centers,
        const int* __restrict__ nbr, const int* __restrict__ nvalid,
        const float* __restrict__ W1, const float* __restrict__ b1,
        const float* __restrict__ W2, const float* __restrict__ b2,
        const float* __restrict__ W3, const float* __restrict__ b3,
        float* __restrict__ out) {
    constexpr int CINF = 67;
    __shared__ __align__(16) float feat[CK * CINF];
    __shared__ __align__(16) float h1[CK * C1];
    __shared__ __align__(16) float h2[CK * C2];
    __shared__ int outmax[C3];
    const int cid = blockIdx.x;
    const int b = cid >> 10;
    const int tid = threadIdx.x;
    const int lane = tid & 63;
    const int wid = tid >> 6;
    const int nv = nvalid[cid];
    const float cx = centers[cid * 3 + 0];
    const float cy = centers[cid * 3 + 1];
    const float cz = centers[cid * 3 + 2];
    for (int i = tid; i < C3; i += 256) outmax[i] = 0;

    for (int k0 = 0; k0 < nv; k0 += CK) {
        __syncthreads();  // protect feat/h reuse and outmax init
        for (int kk = wid; kk < CK; kk += 4) {
            int k = k0 + kk;
            if (k < nv) {
                int pt = nbr[(size_t)cid * K + k];
                const float* xr = x + ((size_t)(b * NP) + pt) * 64;
                feat[kk * CINF + lane] = xr[lane];
                if (lane < 3) {
                    const float* pr = pos + ((size_t)(b * NP) + pt) * 3;
                    float cc = (lane == 0) ? cx : ((lane == 1) ? cy : cz);
                    feat[kk * CINF + 64 + lane] = pr[lane] - cc;
                }
            } else {
                feat[kk * CINF + lane] = 0.f;
                if (lane < 3) feat[kk * CINF + 64 + lane] = 0.f;
            }
        }
        __syncthreads();
        layer_fwd<CK, CINF, C1, 4>(feat, W1, b1, h1, tid);
        __syncthreads();
        layer_fwd<CK, C1, C2, 4>(h1, W2, b2, h2, tid);
        __syncthreads();
        layer_last<CK, C2, C3, 4>(h2, W3, b3, outmax, tid, nv - k0);
    }
    __syncthreads();
    for (int i = tid; i < C3; i += 256)
        out[(size_t)cid * 640 + OFF + i] = __int_as_float(outmax[i]);
}

// ========================= launcher ===========================
extern "C" void kernel_launch(void* const* d_in, const int* in_sizes, int n_in,
                              void* d_out, int out_size, void* d_ws, size_t ws_size,
                              hipStream_t stream) {
    const float* x = (const float*)d_in[0];
    const float* pos = (const float*)d_in[1];
    const float* W0_0 = (const float*)d_in[3];
    const float* b0_0 = (const float*)d_in[4];
    const float* W0_1 = (const float*)d_in[5];
    const float* b0_1 = (const float*)d_in[6];
    const float* W0_2 = (const float*)d_in[7];
    const float* b0_2 = (const float*)d_in[8];
    const float* W1_0 = (const float*)d_in[9];
    const float* b1_0 = (const float*)d_in[10];
    const float* W1_1 = (const float*)d_in[11];
    const float* b1_1 = (const float*)d_in[12];
    const float* W1_2 = (const float*)d_in[13];
    const float* b1_2 = (const float*)d_in[14];
    const float* W2_0 = (const float*)d_in[15];
    const float* b2_0 = (const float*)d_in[16];
    const float* W2_1 = (const float*)d_in[17];
    const float* b2_1 = (const float*)d_in[18];
    const float* W2_2 = (const float*)d_in[19];
    const float* b2_2 = (const float*)d_in[20];

    float* out = (float*)d_out;
    char* ws = (char*)d_ws;
    float* centers = (float*)(ws + 0);                 //  8192*3 f32   = 98304 B
    int* nbr0 = (int*)(ws + 98304);                    //  8192*16 i32  = 524288 B
    int* nbr1 = (int*)(ws + 622592);                   //  8192*32 i32  = 1048576 B
    int* nbr2 = (int*)(ws + 1671168);                  //  8192*64 i32  = 2097152 B
    int* nval = (int*)(ws + 3768320);                  //  3*8192 i32   = 98304 B

    float* out_pos = out + (size_t)8192 * 640;
    float* out_batch = out_pos + (size_t)8192 * 3;

    fps_kernel<<<dim3(NB), dim3(256), 0, stream>>>(pos, centers, out_pos, out_batch);

    select_kernel<16><<<dim3(256), dim3(256), 0, stream>>>(pos, centers, nbr0, nval, (float)(0.1 * 0.1));
    select_kernel<32><<<dim3(256), dim3(256), 0, stream>>>(pos, centers, nbr1, nval + 8192, (float)(0.2 * 0.2));
    select_kernel<64><<<dim3(256), dim3(256), 0, stream>>>(pos, centers, nbr2, nval + 16384, (float)(0.4 * 0.4));

    mlp_kernel<16, 16, 64, 64, 128, 0><<<dim3(8192), dim3(256), 0, stream>>>(
        x, pos, centers, nbr0, nval, W0_0, b0_0, W0_1, b0_1, W0_2, b0_2, out);
    mlp_kernel<32, 32, 128, 128, 256, 128><<<dim3(8192), dim3(256), 0, stream>>>(
        x, pos, centers, nbr1, nval + 8192, W1_0, b1_0, W1_1, b1_1, W1_2, b1_2, out);
    mlp_kernel<64, 32, 128, 128, 256, 384><<<dim3(8192), dim3(256), 0, stream>>>(
        x, pos, centers, nbr2, nval + 16384, W2_0, b2_0, W2_1, b2_1, W2_2, b2_2, out);
}

// Round 3
// 2097.801 us; speedup vs baseline: 2.1298x; 1.7620x over previous
//
#include <hip/hip_runtime.h>

#define NB 8
#define NP 4096
#define NS 1024

typedef _Float16 f16x8 __attribute__((ext_vector_type(8)));
typedef float f32x4 __attribute__((ext_vector_type(4)));

// ============================ FPS =============================
// One block per cloud, 256 threads (4 waves), 16 points/thread in registers.
// Exact match of the reference scan (first index on ties via u64 key).
__global__ __launch_bounds__(256) void fps_kernel(
        const float* __restrict__ pos,
        float* __restrict__ centers,
        float* __restrict__ out_pos,
        float* __restrict__ out_batch) {
#pragma clang fp contract(off)
    const int b = blockIdx.x;
    const int tid = threadIdx.x;
    const int lane = tid & 63;
    const int wid = tid >> 6;
    __shared__ float spx[NP], spy[NP], spz[NP];
    __shared__ unsigned long long wred[8];   // 2 parities x 4 waves

    const float* pb = pos + (size_t)b * NP * 3;
    float px[16], py[16], pz[16], md[16];
#pragma unroll
    for (int j = 0; j < 16; ++j) {
        int p = tid + j * 256;
        float xx = pb[p * 3 + 0];
        float yy = pb[p * 3 + 1];
        float zz = pb[p * 3 + 2];
        px[j] = xx; py[j] = yy; pz[j] = zz;
        md[j] = __builtin_inff();
        spx[p] = xx; spy[p] = yy; spz[p] = zz;
    }
    for (int t = tid; t < NS; t += 256) out_batch[b * NS + t] = (float)b;
    __syncthreads();

    float cx = spx[0], cy = spy[0], cz = spz[0];
    if (tid == 0) {
        size_t o = (size_t)(b * NS) * 3;
        centers[o + 0] = cx; centers[o + 1] = cy; centers[o + 2] = cz;
        out_pos[o + 0] = cx; out_pos[o + 1] = cy; out_pos[o + 2] = cz;
    }

    int par = 0;
    for (int t = 1; t < NS; ++t) {
        float bv = -1.0f;
        int bj = 0;
#pragma unroll
        for (int j = 0; j < 16; ++j) {
            float dx = px[j] - cx; float sx = dx * dx;
            float dy = py[j] - cy; float sy = dy * dy;
            float dz = pz[j] - cz; float sz = dz * dz;
            float d = sx + sy; d = d + sz;
            float m = fminf(md[j], d);
            md[j] = m;
            if (m > bv) { bv = m; bj = j; }
        }
        const int bp = tid + bj * 256;
        unsigned long long best =
            ((unsigned long long)__float_as_uint(bv) << 32) |
            (unsigned)(NP - 1 - bp);
#pragma unroll
        for (int off = 1; off < 64; off <<= 1) {
            unsigned lo = __shfl_xor((unsigned)best, off);
            unsigned hi = __shfl_xor((unsigned)(best >> 32), off);
            unsigned long long o = ((unsigned long long)hi << 32) | lo;
            best = (o > best) ? o : best;
        }
        if (lane == 0) wred[par * 4 + wid] = best;
        __syncthreads();
        {
            unsigned long long b0 = wred[par * 4 + 0];
            unsigned long long b1 = wred[par * 4 + 1];
            unsigned long long b2 = wred[par * 4 + 2];
            unsigned long long b3 = wred[par * 4 + 3];
            unsigned long long m01 = b0 > b1 ? b0 : b1;
            unsigned long long m23 = b2 > b3 ? b2 : b3;
            best = m01 > m23 ? m01 : m23;
        }
        const int bi = NP - 1 - (int)(best & 0xffffffffu);
        cx = spx[bi]; cy = spy[bi]; cz = spz[bi];
        if (tid == 0) {
            size_t o = (size_t)(b * NS + t) * 3;
            centers[o + 0] = cx; centers[o + 1] = cy; centers[o + 2] = cz;
            out_pos[o + 0] = cx; out_pos[o + 1] = cy; out_pos[o + 2] = cz;
        }
        par ^= 1;
    }
}

// ========================= Selection ==========================
// Exact K-nearest within radius r via binary search on uint(d2) bits.
template <int K>
__global__ __launch_bounds__(256) void select_kernel(
        const float* __restrict__ pos,
        const float* __restrict__ centers,
        int* __restrict__ nbr,
        int* __restrict__ nvalid,
        float r2) {
#pragma clang fp contract(off)
    __shared__ float spx[NP], spy[NP], spz[NP];
    const int G = 32;
    const int cbase = blockIdx.x * G;
    const int b = cbase / NS;
    const float* pb = pos + (size_t)b * NP * 3;
    for (int p = threadIdx.x; p < NP; p += 256) {
        spx[p] = pb[p * 3 + 0];
        spy[p] = pb[p * 3 + 1];
        spz[p] = pb[p * 3 + 2];
    }
    __syncthreads();

    const int lane = threadIdx.x & 63;
    const int wid = threadIdx.x >> 6;
    const unsigned kr2 = __float_as_uint(r2);

    for (int c = wid; c < G; c += 4) {
        const int cid = cbase + c;
        const float cx = centers[cid * 3 + 0];
        const float cy = centers[cid * 3 + 1];
        const float cz = centers[cid * 3 + 2];
        unsigned key[64];
#pragma unroll
        for (int i = 0; i < 64; ++i) {
            int p = lane + i * 64;
            float dx = spx[p] - cx; float sx = dx * dx;
            float dy = spy[p] - cy; float sy = dy * dy;
            float dz = spz[p] - cz; float sz = dz * dz;
            float d2 = sx + sy; d2 = d2 + sz;
            key[i] = __float_as_uint(d2);
        }
        int c_cnt = 0;
#pragma unroll
        for (int i = 0; i < 64; ++i)
            c_cnt += __popcll(__ballot(key[i] <= kr2));

        const unsigned long long below = (1ull << lane) - 1ull;
        int nv;
        if (c_cnt <= K) {
            nv = c_cnt;
            int base = 0;
#pragma unroll
            for (int i = 0; i < 64; ++i) {
                unsigned long long m = __ballot(key[i] <= kr2);
                if (key[i] <= kr2) {
                    int slot = base + __popcll(m & below);
                    nbr[(size_t)cid * K + slot] = lane + i * 64;
                }
                base += __popcll(m);
            }
        } else {
            nv = K;
            unsigned lo = 0, hi = kr2;
            while (lo < hi) {
                unsigned mid = lo + ((hi - lo) >> 1);
                int cnt = 0;
#pragma unroll
                for (int i = 0; i < 64; ++i)
                    cnt += __popcll(__ballot(key[i] <= mid));
                if (cnt >= K) hi = mid; else lo = mid + 1;
            }
            const unsigned t = lo;  // K-th smallest key
            int m_cnt = 0;
#pragma unroll
            for (int i = 0; i < 64; ++i)
                m_cnt += __popcll(__ballot(key[i] < t));
            const int rem = K - m_cnt;
            int base = 0, ties = 0;
#pragma unroll
            for (int i = 0; i < 64; ++i) {
                unsigned long long lt = __ballot(key[i] < t);
                unsigned long long eq = __ballot(key[i] == t);
                if (key[i] < t) {
                    int slot = base + __popcll(lt & below);
                    nbr[(size_t)cid * K + slot] = lane + i * 64;
                } else if (key[i] == t) {
                    int tr = ties + __popcll(eq & below);
                    if (tr < rem) nbr[(size_t)cid * K + (m_cnt + tr)] = lane + i * 64;
                }
                base += __popcll(lt);
                ties += __popcll(eq);
            }
        }
        if (lane == 0) nvalid[cid] = nv;
    }
}

// ===================== weight prep (fp32 -> f16, [n][k], K-padded) =====
__global__ __launch_bounds__(256) void prep_w(const float* __restrict__ src,
                                              _Float16* __restrict__ dst,
                                              int Kreal, int Kpad, int Nc) {
    int i = blockIdx.x * 256 + threadIdx.x;
    if (i >= Kpad * Nc) return;
    int n = i / Kpad, k = i - n * Kpad;
    dst[i] = (k < Kreal) ? (_Float16)src[(size_t)k * Nc + n] : (_Float16)0.f;
}

// =========================== MFMA MLP ==============================
// One block = 4 waves splitting N 4 ways; weight fragments resident in VGPRs,
// loaded once per block and reused across NCTR centers. Activations in LDS
// (f16), strides = (K + 8) elems => byte stride == 16 (mod 32): conflict-free
// 16B-aligned ds_read_b128 A-fragments.
// mfma_f32_16x16x32_f16 layouts: A[m=lane&15][k=(lane>>4)*8+j],
// B[k=(lane>>4)*8+j][n=lane&15], D: col=lane&15, row=(lane>>4)*4+reg.
template <int M, int C1, int C2, int C3, int OFF, int NCTR>
__global__ __launch_bounds__(256, 2) void mlp_mfma(
        const float* __restrict__ x, const float* __restrict__ pos,
        const float* __restrict__ centers,
        const int* __restrict__ nbr, const int* __restrict__ nvalid,
        const _Float16* __restrict__ wt1, const _Float16* __restrict__ wt2,
        const _Float16* __restrict__ wt3,
        const float* __restrict__ b1, const float* __restrict__ b2,
        const float* __restrict__ b3,
        float* __restrict__ out) {
    constexpr int K1P = 96;                 // 67 padded to 96
    constexpr int S1 = K1P + 8;             // 104 elems = 208 B
    constexpr int S2 = C1 + 8;              // 72 or 136
    constexpr int S3 = C2 + 8;
    constexpr int MT = M / 16;
    constexpr int NCH1 = C1 / 4, NCH2 = C2 / 4, NCH3 = C3 / 4;
    constexpr int NT1 = NCH1 / 16, NT2 = NCH2 / 16, NT3 = NCH3 / 16;
    constexpr int KT1 = K1P / 32, KT2 = C1 / 32, KT3 = C2 / 32;

    __shared__ __align__(16) _Float16 feat[M * S1];
    __shared__ __align__(16) _Float16 h1[M * S2];
    __shared__ __align__(16) _Float16 h2[M * S3];
    __shared__ int outmax[C3];

    const int tid = threadIdx.x;
    const int lane = tid & 63;
    const int w = tid >> 6;
    const int lm = lane & 15;
    const int lq = lane >> 4;

    // ---- resident weight fragments + biases (per wave N-chunk) ----
    f16x8 wf1[NT1][KT1], wf2[NT2][KT2], wf3[NT3][KT3];
    float bb1[NT1], bb2[NT2], bb3[NT3];
#pragma unroll
    for (int nt = 0; nt < NT1; ++nt) {
        int n = w * NCH1 + nt * 16 + lm;
        bb1[nt] = b1[n];
#pragma unroll
        for (int kt = 0; kt < KT1; ++kt)
            wf1[nt][kt] = *(const f16x8*)(wt1 + (size_t)n * K1P + kt * 32 + lq * 8);
    }
#pragma unroll
    for (int nt = 0; nt < NT2; ++nt) {
        int n = w * NCH2 + nt * 16 + lm;
        bb2[nt] = b2[n];
#pragma unroll
        for (int kt = 0; kt < KT2; ++kt)
            wf2[nt][kt] = *(const f16x8*)(wt2 + (size_t)n * C1 + kt * 32 + lq * 8);
    }
#pragma unroll
    for (int nt = 0; nt < NT3; ++nt) {
        int n = w * NCH3 + nt * 16 + lm;
        bb3[nt] = b3[n];
#pragma unroll
        for (int kt = 0; kt < KT3; ++kt)
            wf3[nt][kt] = *(const f16x8*)(wt3 + (size_t)n * C2 + kt * 32 + lq * 8);
    }

    for (int cc = 0; cc < NCTR; ++cc) {
        const int cid = blockIdx.x * NCTR + cc;
        const int bidx = cid >> 10;
        const int nv = nvalid[cid];
        const float cx = centers[cid * 3 + 0];
        const float cy = centers[cid * 3 + 1];
        const float cz = centers[cid * 3 + 2];
        for (int i = tid; i < C3; i += 256) outmax[i] = 0;

        // ---- gather: 67-ch feature rows -> f16 LDS (zero-padded) ----
#pragma unroll
        for (int i = 0; i < M / 4; ++i) {
            const int r = w * (M / 4) + i;
            if (r < nv) {
                int pt = nbr[(size_t)cid * M + r];
                const float* xr = x + ((size_t)(bidx * NP) + pt) * 64;
                feat[r * S1 + lane] = (_Float16)xr[lane];
                if (lane < 32) {
                    float v = 0.f;
                    if (lane < 3) {
                        float p = pos[((size_t)(bidx * NP) + pt) * 3 + lane];
                        float ccen = (lane == 0) ? cx : ((lane == 1) ? cy : cz);
                        v = p - ccen;
                    }
                    feat[r * S1 + 64 + lane] = (_Float16)v;
                }
            } else {
                feat[r * S1 + lane] = (_Float16)0.f;
                if (lane < 32) feat[r * S1 + 64 + lane] = (_Float16)0.f;
            }
        }
        __syncthreads();

        // ---- layer 1: feat[M x 96] -> h1[M x C1] ----
#pragma unroll
        for (int mt = 0; mt < MT; ++mt) {
            f16x8 a[KT1];
#pragma unroll
            for (int kt = 0; kt < KT1; ++kt)
                a[kt] = *(const f16x8*)(feat + (mt * 16 + lm) * S1 + kt * 32 + lq * 8);
#pragma unroll
            for (int nt = 0; nt < NT1; ++nt) {
                f32x4 acc = {bb1[nt], bb1[nt], bb1[nt], bb1[nt]};
#pragma unroll
                for (int kt = 0; kt < KT1; ++kt)
                    acc = __builtin_amdgcn_mfma_f32_16x16x32_f16(a[kt], wf1[nt][kt], acc, 0, 0, 0);
                const int gc = w * NCH1 + nt * 16 + lm;
#pragma unroll
                for (int rg = 0; rg < 4; ++rg)
                    h1[(mt * 16 + lq * 4 + rg) * S2 + gc] = (_Float16)fmaxf(acc[rg], 0.f);
            }
        }
        __syncthreads();

        // ---- layer 2: h1[M x C1] -> h2[M x C2] ----
#pragma unroll
        for (int mt = 0; mt < MT; ++mt) {
            f16x8 a[KT2];
#pragma unroll
            for (int kt = 0; kt < KT2; ++kt)
                a[kt] = *(const f16x8*)(h1 + (mt * 16 + lm) * S2 + kt * 32 + lq * 8);
#pragma unroll
            for (int nt = 0; nt < NT2; ++nt) {
                f32x4 acc = {bb2[nt], bb2[nt], bb2[nt], bb2[nt]};
#pragma unroll
                for (int kt = 0; kt < KT2; ++kt)
                    acc = __builtin_amdgcn_mfma_f32_16x16x32_f16(a[kt], wf2[nt][kt], acc, 0, 0, 0);
                const int gc = w * NCH2 + nt * 16 + lm;
#pragma unroll
                for (int rg = 0; rg < 4; ++rg)
                    h2[(mt * 16 + lq * 4 + rg) * S3 + gc] = (_Float16)fmaxf(acc[rg], 0.f);
            }
        }
        __syncthreads();

        // ---- layer 3 + masked max ----
#pragma unroll
        for (int mt = 0; mt < MT; ++mt) {
            f16x8 a[KT3];
#pragma unroll
            for (int kt = 0; kt < KT3; ++kt)
                a[kt] = *(const f16x8*)(h2 + (mt * 16 + lm) * S3 + kt * 32 + lq * 8);
#pragma unroll
            for (int nt = 0; nt < NT3; ++nt) {
                f32x4 acc = {bb3[nt], bb3[nt], bb3[nt], bb3[nt]};
#pragma unroll
                for (int kt = 0; kt < KT3; ++kt)
                    acc = __builtin_amdgcn_mfma_f32_16x16x32_f16(a[kt], wf3[nt][kt], acc, 0, 0, 0);
                float mx = -1.f;
#pragma unroll
                for (int rg = 0; rg < 4; ++rg) {
                    int row = mt * 16 + lq * 4 + rg;
                    float v = fmaxf(acc[rg], 0.f);
                    if (row < nv) mx = fmaxf(mx, v);
                }
                mx = fmaxf(mx, __shfl_xor(mx, 16));
                mx = fmaxf(mx, __shfl_xor(mx, 32));
                if (lane < 16)
                    atomicMax(&outmax[w * NCH3 + nt * 16 + lm], __float_as_int(mx));
            }
        }
        __syncthreads();
        for (int i = tid; i < C3; i += 256)
            out[(size_t)cid * 640 + OFF + i] = __int_as_float(outmax[i]);
        __syncthreads();
    }
}

// ========================= launcher ===========================
extern "C" void kernel_launch(void* const* d_in, const int* in_sizes, int n_in,
                              void* d_out, int out_size, void* d_ws, size_t ws_size,
                              hipStream_t stream) {
    const float* x = (const float*)d_in[0];
    const float* pos = (const float*)d_in[1];
    const float* W0_0 = (const float*)d_in[3];
    const float* b0_0 = (const float*)d_in[4];
    const float* W0_1 = (const float*)d_in[5];
    const float* b0_1 = (const float*)d_in[6];
    const float* W0_2 = (const float*)d_in[7];
    const float* b0_2 = (const float*)d_in[8];
    const float* W1_0 = (const float*)d_in[9];
    const float* b1_0 = (const float*)d_in[10];
    const float* W1_1 = (const float*)d_in[11];
    const float* b1_1 = (const float*)d_in[12];
    const float* W1_2 = (const float*)d_in[13];
    const float* b1_2 = (const float*)d_in[14];
    const float* W2_0 = (const float*)d_in[15];
    const float* b2_0 = (const float*)d_in[16];
    const float* W2_1 = (const float*)d_in[17];
    const float* b2_1 = (const float*)d_in[18];
    const float* W2_2 = (const float*)d_in[19];
    const float* b2_2 = (const float*)d_in[20];

    float* out = (float*)d_out;
    char* ws = (char*)d_ws;
    float* centers = (float*)(ws + 0);                 //  98304 B
    int* nbr0 = (int*)(ws + 98304);                    //  524288 B
    int* nbr1 = (int*)(ws + 622592);                   //  1048576 B
    int* nbr2 = (int*)(ws + 1671168);                  //  2097152 B
    int* nval = (int*)(ws + 3768320);                  //  98304 B
    // f16 transposed weights
    _Float16* w0t1 = (_Float16*)(ws + 3866624);        //  64*96  = 12288 B
    _Float16* w0t2 = (_Float16*)(ws + 3878912);        //  64*64  =  8192 B
    _Float16* w0t3 = (_Float16*)(ws + 3887104);        // 128*64  = 16384 B
    _Float16* w1t1 = (_Float16*)(ws + 3903488);        // 128*96  = 24576 B
    _Float16* w1t2 = (_Float16*)(ws + 3928064);        // 128*128 = 32768 B
    _Float16* w1t3 = (_Float16*)(ws + 3960832);        // 256*128 = 65536 B
    _Float16* w2t1 = (_Float16*)(ws + 4026368);
    _Float16* w2t2 = (_Float16*)(ws + 4050944);
    _Float16* w2t3 = (_Float16*)(ws + 4083712);        // end 4149248 B

    float* out_pos = out + (size_t)8192 * 640;
    float* out_batch = out_pos + (size_t)8192 * 3;

    fps_kernel<<<dim3(NB), dim3(256), 0, stream>>>(pos, centers, out_pos, out_batch);

    select_kernel<16><<<dim3(256), dim3(256), 0, stream>>>(pos, centers, nbr0, nval, (float)(0.1 * 0.1));
    select_kernel<32><<<dim3(256), dim3(256), 0, stream>>>(pos, centers, nbr1, nval + 8192, (float)(0.2 * 0.2));
    select_kernel<64><<<dim3(256), dim3(256), 0, stream>>>(pos, centers, nbr2, nval + 16384, (float)(0.4 * 0.4));

    auto prep = [&](const float* src, _Float16* dst, int kr, int kp, int nc) {
        int tot = kp * nc;
        prep_w<<<dim3((tot + 255) / 256), dim3(256), 0, stream>>>(src, dst, kr, kp, nc);
    };
    prep(W0_0, w0t1, 67, 96, 64);
    prep(W0_1, w0t2, 64, 64, 64);
    prep(W0_2, w0t3, 64, 64, 128);
    prep(W1_0, w1t1, 67, 96, 128);
    prep(W1_1, w1t2, 128, 128, 128);
    prep(W1_2, w1t3, 128, 128, 256);
    prep(W2_0, w2t1, 67, 96, 128);
    prep(W2_1, w2t2, 128, 128, 128);
    prep(W2_2, w2t3, 128, 128, 256);

    mlp_mfma<16, 64, 64, 128, 0, 8><<<dim3(1024), dim3(256), 0, stream>>>(
        x, pos, centers, nbr0, nval, w0t1, w0t2, w0t3, b0_0, b0_1, b0_2, out);
    mlp_mfma<32, 128, 128, 256, 128, 8><<<dim3(1024), dim3(256), 0, stream>>>(
        x, pos, centers, nbr1, nval + 8192, w1t1, w1t2, w1t3, b1_0, b1_1, b1_2, out);
    mlp_mfma<64, 128, 128, 256, 384, 8><<<dim3(1024), dim3(256), 0, stream>>>(
        x, pos, centers, nbr2, nval + 16384, w2t1, w2t2, w2t3, b2_0, b2_1, b2_2, out);
}